// Round 8
// baseline (30.064 us; speedup 1.0000x reference)
//
#include <hip/hip_runtime.h>
#include <math.h>

typedef _Float16 f16x8 __attribute__((ext_vector_type(8)));
typedef __fp16   fp16v2 __attribute__((ext_vector_type(2)));
typedef float    f32x16 __attribute__((ext_vector_type(16)));

#define THREADS 256
#define YHALF   4096  // y points per block (half of N), 32 KB LDS
#define XPB     128   // x points per block (4 waves * 32 cols)

static __device__ inline unsigned pk2(float a, float b) {
    fp16v2 h = __builtin_amdgcn_cvt_pkrtz(a, b);
    return __builtin_bit_cast(unsigned, h);
}

// One wave owns 32 x-points (MFMA cols); block scans HALF of y (4096 rows).
// A[y,k] = (y0,y1,y2,|y|^2) f16; B[k,x] = (-2x0,-2x1,-2x2,1) f16, K slots
// 4..15 zero IN B so garbage in A's unused K slots contributes 0.
// acc = d^2 - |x|^2; running min on VALU (v_min3); each block PLAIN-STORES
// its per-point mins to a disjoint ws slot (no atomics, no init kernel).
// 1024 blocks = 4 blocks/CU = 4 waves/SIMD; ILP-4 + occupancy hides latency.
__global__ __launch_bounds__(THREADS, 4) void chamfer_kernel(
    const float* __restrict__ pred, const float* __restrict__ targ,
    float* __restrict__ dmin, int N)
{
    const int dir  = blockIdx.z;
    const int b    = blockIdx.y >> 1;
    const int half = blockIdx.y & 1;
    const float* xsrc = dir == 0 ? pred : targ;
    const float* ysrc = dir == 0 ? targ : pred;

    __shared__ uint2 sy[YHALF];   // (y0,y1) (y2,|y|^2) packed f16

    const int tid  = threadIdx.x;
    const int lane = tid & 63;
    const int wave = tid >> 6;
    const int col  = lane & 31;

    // This lane's x column (lanes 32-63 duplicate lanes 0-31).
    const int    xIdx = blockIdx.x * XPB + wave * 32 + col;
    const size_t xi   = (size_t)(b * N + xIdx) * 3;
    const float x0 = xsrc[xi], x1 = xsrc[xi + 1], x2 = xsrc[xi + 2];

    const bool act = lane < 32;
    f16x8 bf;
    bf[0] = act ? (_Float16)(-2.0f * x0) : (_Float16)0.0f;
    bf[1] = act ? (_Float16)(-2.0f * x1) : (_Float16)0.0f;
    bf[2] = act ? (_Float16)(-2.0f * x2) : (_Float16)0.0f;
    bf[3] = act ? (_Float16)1.0f : (_Float16)0.0f;
    bf[4] = bf[5] = bf[6] = bf[7] = (_Float16)0.0f;

    f32x16 zacc;
    f32x16 vmin;
#pragma unroll
    for (int r = 0; r < 16; ++r) { zacc[r] = 0.0f; vmin[r] = INFINITY; }

    // Stage this block's y-half: float4-vectorized loads (12 instead of 48),
    // 4 points repacked per 3 float4s.
    const float4* yf4 = (const float4*)(ysrc + (size_t)b * N * 3
                                             + (size_t)half * YHALF * 3);
#pragma unroll
    for (int k = 0; k < 4; ++k) {
        const int fbase = k * THREADS * 3 + tid * 3;
        float4 f0 = yf4[fbase + 0];
        float4 f1 = yf4[fbase + 1];
        float4 f2 = yf4[fbase + 2];
        const int yj = (k * THREADS + tid) * 4;
        float n0 = fmaf(f0.x, f0.x, fmaf(f0.y, f0.y, f0.z * f0.z));
        float n1 = fmaf(f0.w, f0.w, fmaf(f1.x, f1.x, f1.y * f1.y));
        float n2 = fmaf(f1.z, f1.z, fmaf(f1.w, f1.w, f2.x * f2.x));
        float n3 = fmaf(f2.y, f2.y, fmaf(f2.z, f2.z, f2.w * f2.w));
        sy[yj + 0] = make_uint2(pk2(f0.x, f0.y), pk2(f0.z, n0));
        sy[yj + 1] = make_uint2(pk2(f0.w, f1.x), pk2(f1.y, n1));
        sy[yj + 2] = make_uint2(pk2(f1.z, f1.w), pk2(f2.x, n2));
        sy[yj + 3] = make_uint2(pk2(f2.y, f2.z), pk2(f2.w, n3));
    }
    __syncthreads();

    // Barrier-free main loop, 4 MFMAs in flight per iteration.
#define LOADJ(j) uint2 lo##j = sy[(i + j) * 32 + col]
#define MFJ(j)                                                            \
    f32x16 ac##j = __builtin_amdgcn_mfma_f32_32x32x16_f16(                \
        __builtin_bit_cast(f16x8,                                         \
            make_uint4(lo##j.x, lo##j.y, 0u, 0u)), bf, zacc, 0, 0, 0)
    for (int i = 0; i < YHALF / 32; i += 4) {
        LOADJ(0); LOADJ(1); LOADJ(2); LOADJ(3);
        MFJ(0); MFJ(1); MFJ(2); MFJ(3);
#pragma unroll
        for (int r = 0; r < 16; ++r) {
            vmin[r] = fminf(fminf(vmin[r], ac0[r]), ac1[r]);  // v_min3
            vmin[r] = fminf(fminf(vmin[r], ac2[r]), ac3[r]);
        }
    }
#undef LOADJ
#undef MFJ

    // Fold 16 regs, then the two row-halves (lane ^ 32) -> full min per col.
    float v = vmin[0];
#pragma unroll
    for (int r = 1; r < 16; ++r) v = fminf(v, vmin[r]);
    v = fminf(v, __shfl_xor(v, 32));
    float d = v + fmaf(x0, x0, fmaf(x1, x1, x2 * x2));  // + |x|^2 in f32

    if (act)
        dmin[(size_t)(((dir * 4 + b) * 2 + half)) * N + xIdx] = d;
}

// Min-merge the two y-halves per point, sum everything, emit (loss,dist,rate).
__global__ __launch_bounds__(1024) void finalize(
    const float* __restrict__ dmin, const float* __restrict__ fbpp,
    float* __restrict__ out, int N, int totalPts)
{
    __shared__ float sw[16];
    const int tid = threadIdx.x;
    float s = 0.0f;
    for (int g = 0; g < 8; ++g) {
        const float4* h0 = (const float4*)(dmin + (size_t)(g * 2 + 0) * N);
        const float4* h1 = (const float4*)(dmin + (size_t)(g * 2 + 1) * N);
        for (int i = tid; i < N / 4; i += 1024) {
            float4 a = h0[i], c = h1[i];
            s += fminf(a.x, c.x) + fminf(a.y, c.y) +
                 fminf(a.z, c.z) + fminf(a.w, c.w);
        }
    }
#pragma unroll
    for (int off = 32; off > 0; off >>= 1) s += __shfl_xor(s, off);
    if ((tid & 63) == 0) sw[tid >> 6] = s;
    __syncthreads();
    if (tid == 0) {
        float t = 0.0f;
#pragma unroll
        for (int w = 0; w < 16; ++w) t += sw[w];
        float dist = t / (float)totalPts;
        float rate = fbpp[0];
        out[0] = dist + rate;
        out[1] = dist;
        out[2] = rate;
    }
}

extern "C" void kernel_launch(void* const* d_in, const int* in_sizes, int n_in,
                              void* d_out, int out_size, void* d_ws, size_t ws_size,
                              hipStream_t stream) {
    const float* pred = (const float*)d_in[0];
    const float* targ = (const float*)d_in[1];
    const float* fbpp = (const float*)d_in[2];
    float* out = (float*)d_out;

    const int B = 4;
    const int N = in_sizes[0] / (B * 3);   // 8192
    float* dmin = (float*)d_ws;            // 2 dirs * 4 b * 2 halves * N = 512 KB

    dim3 grid(N / XPB, B * 2, 2);          // (64, 8, 2) = 1024 blocks
    chamfer_kernel<<<grid, THREADS, 0, stream>>>(pred, targ, dmin, N);

    finalize<<<1, 1024, 0, stream>>>(dmin, fbpp, out, N, B * N);
}

// Round 9
// 25.026 us; speedup vs baseline: 1.2013x; 1.2013x over previous
//
#include <hip/hip_runtime.h>
#include <math.h>

typedef _Float16 f16x8 __attribute__((ext_vector_type(8)));
typedef __fp16   fp16v2 __attribute__((ext_vector_type(2)));
typedef float    f32x16 __attribute__((ext_vector_type(16)));

#define THREADS 512
#define NPTS    8192  // all y points staged per block (64 KB LDS)
#define XPB     128   // x cols per block = 4 col-groups * 32

static __device__ inline unsigned pk2(float a, float b) {
    fp16v2 h = __builtin_amdgcn_cvt_pkrtz(a, b);
    return __builtin_bit_cast(unsigned, h);
}

// Block owns 128 x-cols; stages ALL 8192 y once (64 KB LDS).
// 8 waves: wave w = {col-group g = w&3, y-half = w>>2}. Waves 0-3 scan
// half 0, waves 4-7 scan half 1 for the same col-groups; halves merge via
// a tiny LDS array -> block emits ONE partial sum (no global min traffic).
// A[y,k]=(y0,y1,y2,|y|^2) f16; B[k,x]=(-2x0,-2x1,-2x2,1) f16, other K slots
// zero IN B so garbage in A's unused K slots contributes 0.
// acc = d^2 - |x|^2; running min on VALU (v_min3); |x|^2 added in f32.
// 512 blocks * 8 waves = 4096 waves = 4 waves/SIMD (VGPR<=128, ILP-4).
__global__ __launch_bounds__(THREADS, 4) void chamfer_kernel(
    const float* __restrict__ pred, const float* __restrict__ targ,
    float* __restrict__ partials, int N)
{
    const int dir = blockIdx.z;
    const float* xsrc = dir == 0 ? pred : targ;
    const float* ysrc = dir == 0 ? targ : pred;
    const int b = blockIdx.y;

    __shared__ uint2 sy[NPTS];     // (y0,y1) (y2,|y|^2) packed f16
    __shared__ float sd[8][32];    // per-wave per-col d (pre-merge)
    __shared__ float ssum[2];

    const int tid  = threadIdx.x;
    const int lane = tid & 63;
    const int wave = tid >> 6;     // 0..7
    const int g    = wave & 3;     // col group
    const int half = wave >> 2;    // y half
    const int col  = lane & 31;

    // This lane's x column (lanes 32-63 duplicate lanes 0-31).
    const int    xIdx = blockIdx.x * XPB + g * 32 + col;
    const size_t xi   = (size_t)(b * N + xIdx) * 3;
    const float x0 = xsrc[xi], x1 = xsrc[xi + 1], x2 = xsrc[xi + 2];

    const bool act = lane < 32;
    f16x8 bf;
    bf[0] = act ? (_Float16)(-2.0f * x0) : (_Float16)0.0f;
    bf[1] = act ? (_Float16)(-2.0f * x1) : (_Float16)0.0f;
    bf[2] = act ? (_Float16)(-2.0f * x2) : (_Float16)0.0f;
    bf[3] = act ? (_Float16)1.0f : (_Float16)0.0f;
    bf[4] = bf[5] = bf[6] = bf[7] = (_Float16)0.0f;

    f32x16 zacc;
    f32x16 vmin;
#pragma unroll
    for (int r = 0; r < 16; ++r) { zacc[r] = 0.0f; vmin[r] = INFINITY; }

    // Stage all 8192 y: float4-vectorized (12 loads/thread, 4 pts / 3 f4s).
    const float4* yf4 = (const float4*)(ysrc + (size_t)b * N * 3);
#pragma unroll
    for (int k = 0; k < 4; ++k) {
        const int fbase = k * THREADS * 3 + tid * 3;
        float4 f0 = yf4[fbase + 0];
        float4 f1 = yf4[fbase + 1];
        float4 f2 = yf4[fbase + 2];
        const int yj = (k * THREADS + tid) * 4;
        float n0 = fmaf(f0.x, f0.x, fmaf(f0.y, f0.y, f0.z * f0.z));
        float n1 = fmaf(f0.w, f0.w, fmaf(f1.x, f1.x, f1.y * f1.y));
        float n2 = fmaf(f1.z, f1.z, fmaf(f1.w, f1.w, f2.x * f2.x));
        float n3 = fmaf(f2.y, f2.y, fmaf(f2.z, f2.z, f2.w * f2.w));
        sy[yj + 0] = make_uint2(pk2(f0.x, f0.y), pk2(f0.z, n0));
        sy[yj + 1] = make_uint2(pk2(f0.w, f1.x), pk2(f1.y, n1));
        sy[yj + 2] = make_uint2(pk2(f1.z, f1.w), pk2(f2.x, n2));
        sy[yj + 3] = make_uint2(pk2(f2.y, f2.z), pk2(f2.w, n3));
    }
    __syncthreads();

    // Barrier-free main loop over this wave's y-half, 4 MFMAs in flight.
    const int base = half * (NPTS / 2);
#define LOADJ(j) uint2 lo##j = sy[base + (i + j) * 32 + col]
#define MFJ(j)                                                            \
    f32x16 ac##j = __builtin_amdgcn_mfma_f32_32x32x16_f16(                \
        __builtin_bit_cast(f16x8,                                         \
            make_uint4(lo##j.x, lo##j.y, 0u, 0u)), bf, zacc, 0, 0, 0)
    for (int i = 0; i < (NPTS / 2) / 32; i += 4) {
        LOADJ(0); LOADJ(1); LOADJ(2); LOADJ(3);
        MFJ(0); MFJ(1); MFJ(2); MFJ(3);
#pragma unroll
        for (int r = 0; r < 16; ++r) {
            vmin[r] = fminf(fminf(vmin[r], ac0[r]), ac1[r]);  // v_min3
            vmin[r] = fminf(fminf(vmin[r], ac2[r]), ac3[r]);
        }
    }
#undef LOADJ
#undef MFJ

    // Fold 16 regs, then the two row-halves (lane ^ 32) -> min over this
    // wave's y-half for its col; add |x|^2 in f32.
    float v = vmin[0];
#pragma unroll
    for (int r = 1; r < 16; ++r) v = fminf(v, vmin[r]);
    v = fminf(v, __shfl_xor(v, 32));
    float d = v + fmaf(x0, x0, fmaf(x1, x1, x2 * x2));

    if (act) sd[wave][col] = d;
    __syncthreads();

    // Merge y-halves (wave w vs w+4) and sum the 128 cols (2 waves).
    if (tid < 128) {
        float m = fminf(sd[tid >> 5][tid & 31], sd[(tid >> 5) + 4][tid & 31]);
#pragma unroll
        for (int off = 32; off > 0; off >>= 1) m += __shfl_xor(m, off);
        if ((tid & 63) == 0) ssum[tid >> 6] = m;
    }
    __syncthreads();
    if (tid == 0) {
        int bid = blockIdx.x + gridDim.x * (blockIdx.y + gridDim.y * blockIdx.z);
        partials[bid] = ssum[0] + ssum[1];
    }
}

// Sum all 512 block partials; dist = sum / (B*N); out = (loss, dist, rate).
__global__ __launch_bounds__(512) void finalize(
    const float* __restrict__ partials, const float* __restrict__ fbpp,
    float* __restrict__ out, int nPartials, int totalPts)
{
    __shared__ float sw[8];
    const int tid = threadIdx.x;
    float v = (tid < nPartials) ? partials[tid] : 0.0f;
#pragma unroll
    for (int off = 32; off > 0; off >>= 1) v += __shfl_xor(v, off);
    if ((tid & 63) == 0) sw[tid >> 6] = v;
    __syncthreads();
    if (tid == 0) {
        float t = 0.0f;
#pragma unroll
        for (int w = 0; w < 8; ++w) t += sw[w];
        float dist = t / (float)totalPts;
        float rate = fbpp[0];
        out[0] = dist + rate;
        out[1] = dist;
        out[2] = rate;
    }
}

extern "C" void kernel_launch(void* const* d_in, const int* in_sizes, int n_in,
                              void* d_out, int out_size, void* d_ws, size_t ws_size,
                              hipStream_t stream) {
    const float* pred = (const float*)d_in[0];
    const float* targ = (const float*)d_in[1];
    const float* fbpp = (const float*)d_in[2];
    float* out = (float*)d_out;

    const int B = 4;
    const int N = in_sizes[0] / (B * 3);   // 8192
    float* partials = (float*)d_ws;        // 2 * B * (N/XPB) floats = 512

    dim3 grid(N / XPB, B, 2);              // (64, 4, 2) = 512 blocks
    chamfer_kernel<<<grid, THREADS, 0, stream>>>(pred, targ, partials, N);

    const int nPartials = (N / XPB) * B * 2;  // 512
    finalize<<<1, 512, 0, stream>>>(partials, fbpp, out, nPartials, B * N);
}